// Round 1
// baseline (935.017 us; speedup 1.0000x reference)
//
#include <hip/hip_runtime.h>
#include <math.h>

namespace {

constexpr int B = 2, C = 64, H = 80, W = 80, N = H * W;  // N = 6400
constexpr int NQ = 1600;   // 40*40
constexpr int C8 = 8;
constexpr float EPS = 1e-5f;
constexpr int SCH = 8;     // pam_stats m-chunks
constexpr int SAP = 4;     // pam_apply m-splits

// ---------------- conv 3x3, pad 1, no bias ----------------
__global__ void conv3x3_k(const float* __restrict__ in, const float* __restrict__ wgt,
                          float* __restrict__ out) {
  const int b = blockIdx.z, co = blockIdx.y;
  const int p = blockIdx.x * 256 + threadIdx.x;  // 0..6399
  __shared__ float wsm[C * 9];
  for (int i = threadIdx.x; i < C * 9; i += 256) wsm[i] = wgt[co * C * 9 + i];
  __syncthreads();
  const int h = p / W, w0 = p % W;
  float acc = 0.f;
  const float* inb = in + (size_t)b * C * N;
  for (int ci = 0; ci < C; ++ci) {
    const float* xp = inb + ci * N;
    const float* wp = wsm + ci * 9;
#pragma unroll
    for (int kh = 0; kh < 3; ++kh) {
      const int hh = h + kh - 1;
      if ((unsigned)hh < (unsigned)H) {
        const float* row = xp + hh * W;
        const float wa = wp[kh * 3 + 0], wb = wp[kh * 3 + 1], wc = wp[kh * 3 + 2];
        if (w0 >= 1) acc = fmaf(wa, row[w0 - 1], acc);
        acc = fmaf(wb, row[w0], acc);
        if (w0 < W - 1) acc = fmaf(wc, row[w0 + 1], acc);
      }
    }
  }
  out[((size_t)b * C + co) * N + p] = acc;
}

// ---------------- BN batch stats (mean/invstd over B*H*W per channel) ----------------
__global__ void bn_stats_k(const float* __restrict__ y, float* __restrict__ mean,
                           float* __restrict__ istd) {
  const int c = blockIdx.x;
  float s = 0.f, s2 = 0.f;
  for (int i = threadIdx.x; i < B * N; i += 256) {
    const int b = i / N, n = i - b * N;
    const float v = y[((size_t)b * C + c) * N + n];
    s += v;
    s2 = fmaf(v, v, s2);
  }
#pragma unroll
  for (int off = 1; off < 64; off <<= 1) {
    s += __shfl_xor(s, off);
    s2 += __shfl_xor(s2, off);
  }
  __shared__ float rs[4], rs2[4];
  const int wid = threadIdx.x >> 6, lid = threadIdx.x & 63;
  if (lid == 0) { rs[wid] = s; rs2[wid] = s2; }
  __syncthreads();
  if (threadIdx.x == 0) {
    float ts = rs[0] + rs[1] + rs[2] + rs[3];
    float t2 = rs2[0] + rs2[1] + rs2[2] + rs2[3];
    const float m = ts / (float)(B * N);
    const float var = t2 / (float)(B * N) - m * m;
    mean[c] = m;
    istd[c] = rsqrtf(var + EPS);
  }
}

// ---------------- BN apply (optional relu) ----------------
__global__ void bn_apply_k(const float* __restrict__ y, const float* __restrict__ mean,
                           const float* __restrict__ istd, const float* __restrict__ g,
                           const float* __restrict__ bta, float* __restrict__ out, int relu) {
  const int idx = blockIdx.x * 256 + threadIdx.x;  // < B*C*N
  const int c = (idx / N) % C;
  float v = (y[idx] - mean[c]) * istd[c] * g[c] + bta[c];
  if (relu) v = fmaxf(v, 0.f);
  out[idx] = v;
}

// ---------------- conv 2x2 stride 2, bias ----------------
__global__ void conv2x2s2_k(const float* __restrict__ in, const float* __restrict__ wgt,
                            const float* __restrict__ bias, float* __restrict__ out) {
  const int b = blockIdx.z, co = blockIdx.y;
  const int p = blockIdx.x * 256 + threadIdx.x;  // < 1600 (guarded)
  __shared__ float wsm[C * 4];
  for (int i = threadIdx.x; i < C * 4; i += 256) wsm[i] = wgt[co * C * 4 + i];
  __syncthreads();
  if (p >= NQ) return;
  const int oh = p / 40, ow = p - oh * 40;
  const float* inb = in + (size_t)b * C * N + (oh * 2) * W + ow * 2;
  float acc = bias[co];
  for (int ci = 0; ci < C; ++ci) {
    const float* xp = inb + ci * N;
    const float* wp = wsm + ci * 4;
    acc = fmaf(wp[0], xp[0], acc);
    acc = fmaf(wp[1], xp[1], acc);
    acc = fmaf(wp[2], xp[W], acc);
    acc = fmaf(wp[3], xp[W + 1], acc);
  }
  out[((size_t)b * C + co) * NQ + p] = acc;
}

// ---------------- conv 1x1, bias, Cout channels ----------------
__global__ void conv1x1_k(const float* __restrict__ in, const float* __restrict__ wgt,
                          const float* __restrict__ bias, float* __restrict__ out, int Cout) {
  const int b = blockIdx.z, co = blockIdx.y;
  const int p = blockIdx.x * 256 + threadIdx.x;
  __shared__ float wsm[C];
  if (threadIdx.x < C) wsm[threadIdx.x] = wgt[co * C + threadIdx.x];
  __syncthreads();
  float acc = bias[co];
  const float* inb = in + (size_t)b * C * N + p;
#pragma unroll 8
  for (int ci = 0; ci < C; ++ci) acc = fmaf(wsm[ci], inb[ci * N], acc);
  out[((size_t)b * Cout + co) * N + p] = acc;
}

// ---------------- CAM: energy + (max - e) softmax fused; one wave per (b,c) row ----------------
__global__ void cam_attn_k(const float* __restrict__ q, const float* __restrict__ k,
                           float* __restrict__ attn) {
  const int b = blockIdx.y, c = blockIdx.x, d = threadIdx.x;  // block = 64 threads
  const float* qp = q + ((size_t)b * C + c) * NQ;
  const float* kp = k + ((size_t)b * C + d) * NQ;
  float s0 = 0.f, s1 = 0.f, s2 = 0.f, s3 = 0.f;
  for (int n = 0; n < NQ; n += 4) {
    s0 = fmaf(qp[n + 0], kp[n + 0], s0);
    s1 = fmaf(qp[n + 1], kp[n + 1], s1);
    s2 = fmaf(qp[n + 2], kp[n + 2], s2);
    s3 = fmaf(qp[n + 3], kp[n + 3], s3);
  }
  const float e = (s0 + s1) + (s2 + s3);
  float rmax = e;
#pragma unroll
  for (int m = 1; m < 64; m <<= 1) rmax = fmaxf(rmax, __shfl_xor(rmax, m));
  const float e2 = rmax - e;  // energy.max(-1) - energy
  float m2 = e2;
#pragma unroll
  for (int m = 1; m < 64; m <<= 1) m2 = fmaxf(m2, __shfl_xor(m2, m));
  const float pexp = __expf(e2 - m2);
  float ssum = pexp;
#pragma unroll
  for (int m = 1; m < 64; m <<= 1) ssum += __shfl_xor(ssum, m);
  attn[((size_t)b * C + c) * C + d] = pexp / ssum;
}

// ---------------- PAM stats: per-row (over m-chunk) max and sum-exp ----------------
__global__ void pam_stats_k(const float* __restrict__ pq, const float* __restrict__ pk,
                            float* __restrict__ Mp, float* __restrict__ Lp) {
  const int b = blockIdx.z;
  const int n = blockIdx.y * 256 + threadIdx.x;  // 0..6399
  const int chunk = blockIdx.x;
  const int m0 = chunk * (N / SCH), m1 = m0 + (N / SCH);
  float qv[8];
#pragma unroll
  for (int j = 0; j < 8; ++j) qv[j] = pq[((size_t)b * C8 + j) * N + n];
  const float* kbp = pk + (size_t)b * C8 * N;
  float mx = -1e30f;
#pragma unroll 2
  for (int m = m0; m < m1; ++m) {
    float s = 0.f;
#pragma unroll
    for (int j = 0; j < 8; ++j) s = fmaf(qv[j], kbp[j * N + m], s);
    mx = fmaxf(mx, s);
  }
  float l = 0.f;
#pragma unroll 2
  for (int m = m0; m < m1; ++m) {
    float s = 0.f;
#pragma unroll
    for (int j = 0; j < 8; ++j) s = fmaf(qv[j], kbp[j * N + m], s);
    l += __expf(s - mx);
  }
  const int ng = b * N + n;
  Mp[chunk * (B * N) + ng] = mx;
  Lp[chunk * (B * N) + ng] = l;
}

// ---------------- PAM merge chunk stats -> row max, 1/L ----------------
__global__ void pam_merge_k(const float* __restrict__ Mp, const float* __restrict__ Lp,
                            float* __restrict__ Mr, float* __restrict__ Li) {
  const int ng = blockIdx.x * 256 + threadIdx.x;  // < B*N
  float mx = -1e30f;
#pragma unroll
  for (int s = 0; s < SCH; ++s) mx = fmaxf(mx, Mp[s * (B * N) + ng]);
  float l = 0.f;
#pragma unroll
  for (int s = 0; s < SCH; ++s) l = fmaf(Lp[s * (B * N) + ng], __expf(Mp[s * (B * N) + ng] - mx), l);
  Mr[ng] = mx;
  Li[ng] = 1.f / l;
}

// ---------------- PAM apply: sc[c,n] = sum_m w[n,m] * pv[c,m], tiled, m-split ----------------
__global__ __launch_bounds__(256) void pam_apply_k(
    const float* __restrict__ pq, const float* __restrict__ pk, const float* __restrict__ pv,
    const float* __restrict__ Mr, const float* __restrict__ Li, float* __restrict__ scp) {
  const int b = blockIdx.z, mc = blockIdx.y, nt = blockIdx.x;
  const int n_base = nt * 64;
  __shared__ __align__(16) float pk_s[64][8];   // [m][j]
  __shared__ __align__(16) float pv_s[64][68];  // [m][c] (padded, 16B rows)
  __shared__ __align__(16) float w_s[64][68];   // [m][n] (padded, 16B rows)
  const int t = threadIdx.x;
  const int tm = t & 15;   // c-group for acc, m-group for w-compute
  const int tn = t >> 4;   // n-group (consistent across phases)

  float qreg[4][8], Mreg[4], Lireg[4];
#pragma unroll
  for (int nn = 0; nn < 4; ++nn) {
    const int n = n_base + tn * 4 + nn;
#pragma unroll
    for (int j = 0; j < 8; ++j) qreg[nn][j] = pq[((size_t)b * C8 + j) * N + n];
    Mreg[nn] = Mr[b * N + n];
    Lireg[nn] = Li[b * N + n];
  }

  float acc[4][4];
#pragma unroll
  for (int i = 0; i < 4; ++i)
#pragma unroll
    for (int j = 0; j < 4; ++j) acc[i][j] = 0.f;

  for (int mt = 0; mt < N / (SAP * 64); ++mt) {
    const int m0 = (mc * (N / (SAP * 64)) + mt) * 64;
    // stage pk tile: 512 floats
    for (int i = t; i < 512; i += 256) {
      const int j = i >> 6, m = i & 63;
      pk_s[m][j] = pk[((size_t)b * C8 + j) * N + m0 + m];
    }
    // stage pv tile transposed: 4096 floats
    for (int i = t; i < 4096; i += 256) {
      const int c = i >> 6, m = i & 63;
      pv_s[m][c] = pv[((size_t)b * C + c) * N + m0 + m];
    }
    __syncthreads();
    // compute w tile: thread does m in [tm*4, tm*4+4), its 4 n's
#pragma unroll
    for (int mi = 0; mi < 4; ++mi) {
      const int mm = tm * 4 + mi;
      const float4 kf0 = *(const float4*)&pk_s[mm][0];
      const float4 kf1 = *(const float4*)&pk_s[mm][4];
      float wv[4];
#pragma unroll
      for (int nn = 0; nn < 4; ++nn) {
        float s = kf0.x * qreg[nn][0];
        s = fmaf(kf0.y, qreg[nn][1], s);
        s = fmaf(kf0.z, qreg[nn][2], s);
        s = fmaf(kf0.w, qreg[nn][3], s);
        s = fmaf(kf1.x, qreg[nn][4], s);
        s = fmaf(kf1.y, qreg[nn][5], s);
        s = fmaf(kf1.z, qreg[nn][6], s);
        s = fmaf(kf1.w, qreg[nn][7], s);
        wv[nn] = __expf(s - Mreg[nn]) * Lireg[nn];
      }
      *(float4*)&w_s[mm][tn * 4] = make_float4(wv[0], wv[1], wv[2], wv[3]);
    }
    __syncthreads();
    // accumulate: acc[c-group tm][n-group tn]
#pragma unroll 4
    for (int mm = 0; mm < 64; ++mm) {
      const float4 wf = *(const float4*)&w_s[mm][tn * 4];
      const float4 vf = *(const float4*)&pv_s[mm][tm * 4];
      acc[0][0] = fmaf(vf.x, wf.x, acc[0][0]);
      acc[0][1] = fmaf(vf.x, wf.y, acc[0][1]);
      acc[0][2] = fmaf(vf.x, wf.z, acc[0][2]);
      acc[0][3] = fmaf(vf.x, wf.w, acc[0][3]);
      acc[1][0] = fmaf(vf.y, wf.x, acc[1][0]);
      acc[1][1] = fmaf(vf.y, wf.y, acc[1][1]);
      acc[1][2] = fmaf(vf.y, wf.z, acc[1][2]);
      acc[1][3] = fmaf(vf.y, wf.w, acc[1][3]);
      acc[2][0] = fmaf(vf.z, wf.x, acc[2][0]);
      acc[2][1] = fmaf(vf.z, wf.y, acc[2][1]);
      acc[2][2] = fmaf(vf.z, wf.z, acc[2][2]);
      acc[2][3] = fmaf(vf.z, wf.w, acc[2][3]);
      acc[3][0] = fmaf(vf.w, wf.x, acc[3][0]);
      acc[3][1] = fmaf(vf.w, wf.y, acc[3][1]);
      acc[3][2] = fmaf(vf.w, wf.z, acc[3][2]);
      acc[3][3] = fmaf(vf.w, wf.w, acc[3][3]);
    }
    __syncthreads();
  }
  // write partial: scp[mc][b][c][n]
  float* outp = scp + ((size_t)(mc * B + b)) * C * N;
#pragma unroll
  for (int cc = 0; cc < 4; ++cc) {
    const int c = tm * 4 + cc;
    *(float4*)&outp[(size_t)c * N + n_base + tn * 4] =
        make_float4(acc[cc][0], acc[cc][1], acc[cc][2], acc[cc][3]);
  }
}

// ---------------- combine: feat_sum = feat1 + g1*(attn_c @ v) + g2*sum(sc partials) ----------------
__global__ void combine_k(const float* __restrict__ attn, const float* __restrict__ v,
                          const float* __restrict__ feat1, const float* __restrict__ scp,
                          const float* __restrict__ g1, const float* __restrict__ g2,
                          float* __restrict__ fsum) {
  const int b = blockIdx.z, c = blockIdx.y;
  const int p = blockIdx.x * 256 + threadIdx.x;
  __shared__ float as_[C];
  if (threadIdx.x < C) as_[threadIdx.x] = attn[((size_t)b * C + c) * C + threadIdx.x];
  __syncthreads();
  float acc = 0.f;
  const float* vb = v + (size_t)b * C * N + p;
#pragma unroll 8
  for (int d = 0; d < C; ++d) acc = fmaf(as_[d], vb[d * N], acc);
  const size_t idx = ((size_t)b * C + c) * N + p;
  float sc = 0.f;
#pragma unroll
  for (int s = 0; s < SAP; ++s) sc += scp[(size_t)s * B * C * N + idx];
  fsum[idx] = fmaf(g1[0], acc, fmaf(g2[0], sc, feat1[idx]));
}

}  // namespace

extern "C" void kernel_launch(void* const* d_in, const int* in_sizes, int n_in,
                              void* d_out, int out_size, void* d_ws, size_t ws_size,
                              hipStream_t stream) {
  (void)in_sizes; (void)n_in; (void)out_size; (void)ws_size;
  const float* x    = (const float*)d_in[0];
  const float* Wc   = (const float*)d_in[1];
  const float* bn1g = (const float*)d_in[2];
  const float* bn1b = (const float*)d_in[3];
  const float* cqw  = (const float*)d_in[4];
  const float* cqb  = (const float*)d_in[5];
  const float* ckw  = (const float*)d_in[6];
  const float* ckb  = (const float*)d_in[7];
  const float* cvw  = (const float*)d_in[8];
  const float* cvb  = (const float*)d_in[9];
  const float* pqw  = (const float*)d_in[10];
  const float* pqb  = (const float*)d_in[11];
  const float* pkw  = (const float*)d_in[12];
  const float* pkb  = (const float*)d_in[13];
  const float* pvw  = (const float*)d_in[14];
  const float* pvb  = (const float*)d_in[15];
  const float* g1   = (const float*)d_in[16];
  const float* g2   = (const float*)d_in[17];
  const float* bn2g = (const float*)d_in[18];
  const float* bn2b = (const float*)d_in[19];
  const float* Wd   = (const float*)d_in[20];
  const float* bn3g = (const float*)d_in[21];
  const float* bn3b = (const float*)d_in[22];
  float* out = (float*)d_out;

  float* wsp = (float*)d_ws;
  size_t off = 0;
  auto alloc = [&](size_t nel) { float* p = wsp + off; off += nel; return p; };
  float* feat1 = alloc((size_t)B * C * N);
  float* y1    = alloc((size_t)B * C * N);
  float* qb    = alloc((size_t)B * C * NQ);
  float* kb    = alloc((size_t)B * C * NQ);
  float* vb    = alloc((size_t)B * C * N);
  float* attn  = alloc((size_t)B * C * C);
  float* pq    = alloc((size_t)B * C8 * N);
  float* pk    = alloc((size_t)B * C8 * N);
  float* pv    = alloc((size_t)B * C * N);
  float* scp   = alloc((size_t)SAP * B * C * N);
  float* Mp    = alloc((size_t)SCH * B * N);
  float* Lp    = alloc((size_t)SCH * B * N);
  float* Mr    = alloc((size_t)B * N);
  float* Li    = alloc((size_t)B * N);
  float* fsum  = alloc((size_t)B * C * N);
  float* x2    = alloc((size_t)B * C * N);
  float* y3    = alloc((size_t)B * C * N);
  float* mean1 = alloc(C); float* istd1 = alloc(C);
  float* mean2 = alloc(C); float* istd2 = alloc(C);
  float* mean3 = alloc(C); float* istd3 = alloc(C);

  // conv_c -> bn1 -> relu
  conv3x3_k<<<dim3(N / 256, C, B), 256, 0, stream>>>(x, Wc, y1);
  bn_stats_k<<<dim3(C), 256, 0, stream>>>(y1, mean1, istd1);
  bn_apply_k<<<dim3(B * C * N / 256), 256, 0, stream>>>(y1, mean1, istd1, bn1g, bn1b, feat1, 1);
  // CAM inputs
  conv2x2s2_k<<<dim3(7, C, B), 256, 0, stream>>>(feat1, cqw, cqb, qb);
  conv2x2s2_k<<<dim3(7, C, B), 256, 0, stream>>>(feat1, ckw, ckb, kb);
  conv1x1_k<<<dim3(N / 256, C, B), 256, 0, stream>>>(feat1, cvw, cvb, vb, C);
  // PAM inputs
  conv1x1_k<<<dim3(N / 256, C8, B), 256, 0, stream>>>(feat1, pqw, pqb, pq, C8);
  conv1x1_k<<<dim3(N / 256, C8, B), 256, 0, stream>>>(feat1, pkw, pkb, pk, C8);
  conv1x1_k<<<dim3(N / 256, C, B), 256, 0, stream>>>(feat1, pvw, pvb, pv, C);
  // CAM attention
  cam_attn_k<<<dim3(C, B), 64, 0, stream>>>(qb, kb, attn);
  // PAM softmax stats + apply
  pam_stats_k<<<dim3(SCH, N / 256, B), 256, 0, stream>>>(pq, pk, Mp, Lp);
  pam_merge_k<<<dim3(B * N / 256), 256, 0, stream>>>(Mp, Lp, Mr, Li);
  pam_apply_k<<<dim3(N / 64, SAP, B), 256, 0, stream>>>(pq, pk, pv, Mr, Li, scp);
  // combine
  combine_k<<<dim3(N / 256, C, B), 256, 0, stream>>>(attn, vb, feat1, scp, g1, g2, fsum);
  // bn2 -> conv_d -> bn3 -> relu
  bn_stats_k<<<dim3(C), 256, 0, stream>>>(fsum, mean2, istd2);
  bn_apply_k<<<dim3(B * C * N / 256), 256, 0, stream>>>(fsum, mean2, istd2, bn2g, bn2b, x2, 0);
  conv3x3_k<<<dim3(N / 256, C, B), 256, 0, stream>>>(x2, Wd, y3);
  bn_stats_k<<<dim3(C), 256, 0, stream>>>(y3, mean3, istd3);
  bn_apply_k<<<dim3(B * C * N / 256), 256, 0, stream>>>(y3, mean3, istd3, bn3g, bn3b, out, 1);
}

// Round 2
// 629.215 us; speedup vs baseline: 1.4860x; 1.4860x over previous
//
#include <hip/hip_runtime.h>
#include <math.h>

namespace {

constexpr int B = 2, C = 64, H = 80, W = 80, N = H * W;  // N = 6400
constexpr int NQ = 1600;   // 40*40
constexpr int C8 = 8;
constexpr float EPS = 1e-5f;
constexpr int SAP = 8;           // pam flash m-chunks
constexpr int MCH = N / SAP;     // 800 m per chunk

typedef __attribute__((ext_vector_type(8))) short bf16x8;
typedef __attribute__((ext_vector_type(4))) float f32x4;

union U4H8 { uint4 u; bf16x8 h; };
union H8U { unsigned short s[8]; bf16x8 h; };

__device__ __forceinline__ unsigned short f2bf(float x) {
  unsigned u = __builtin_bit_cast(unsigned, x);
  u += 0x7fffu + ((u >> 16) & 1u);   // RNE (no NaN inputs here)
  return (unsigned short)(u >> 16);
}

// ---------------- conv 3x3, pad 1, no bias ----------------
__global__ void conv3x3_k(const float* __restrict__ in, const float* __restrict__ wgt,
                          float* __restrict__ out) {
  const int b = blockIdx.z, co = blockIdx.y;
  const int p = blockIdx.x * 256 + threadIdx.x;  // 0..6399
  __shared__ float wsm[C * 9];
  for (int i = threadIdx.x; i < C * 9; i += 256) wsm[i] = wgt[co * C * 9 + i];
  __syncthreads();
  const int h = p / W, w0 = p % W;
  float acc = 0.f;
  const float* inb = in + (size_t)b * C * N;
  for (int ci = 0; ci < C; ++ci) {
    const float* xp = inb + ci * N;
    const float* wp = wsm + ci * 9;
#pragma unroll
    for (int kh = 0; kh < 3; ++kh) {
      const int hh = h + kh - 1;
      if ((unsigned)hh < (unsigned)H) {
        const float* row = xp + hh * W;
        const float wa = wp[kh * 3 + 0], wb = wp[kh * 3 + 1], wc = wp[kh * 3 + 2];
        if (w0 >= 1) acc = fmaf(wa, row[w0 - 1], acc);
        acc = fmaf(wb, row[w0], acc);
        if (w0 < W - 1) acc = fmaf(wc, row[w0 + 1], acc);
      }
    }
  }
  out[((size_t)b * C + co) * N + p] = acc;
}

// ---------------- BN batch stats ----------------
__global__ void bn_stats_k(const float* __restrict__ y, float* __restrict__ mean,
                           float* __restrict__ istd) {
  const int c = blockIdx.x;
  float s = 0.f, s2 = 0.f;
  for (int i = threadIdx.x; i < B * N; i += 256) {
    const int b = i / N, n = i - b * N;
    const float v = y[((size_t)b * C + c) * N + n];
    s += v;
    s2 = fmaf(v, v, s2);
  }
#pragma unroll
  for (int off = 1; off < 64; off <<= 1) {
    s += __shfl_xor(s, off);
    s2 += __shfl_xor(s2, off);
  }
  __shared__ float rs[4], rs2[4];
  const int wid = threadIdx.x >> 6, lid = threadIdx.x & 63;
  if (lid == 0) { rs[wid] = s; rs2[wid] = s2; }
  __syncthreads();
  if (threadIdx.x == 0) {
    float ts = rs[0] + rs[1] + rs[2] + rs[3];
    float t2 = rs2[0] + rs2[1] + rs2[2] + rs2[3];
    const float m = ts / (float)(B * N);
    const float var = t2 / (float)(B * N) - m * m;
    mean[c] = m;
    istd[c] = rsqrtf(var + EPS);
  }
}

// ---------------- BN apply (optional relu) ----------------
__global__ void bn_apply_k(const float* __restrict__ y, const float* __restrict__ mean,
                           const float* __restrict__ istd, const float* __restrict__ g,
                           const float* __restrict__ bta, float* __restrict__ out, int relu) {
  const int idx = blockIdx.x * 256 + threadIdx.x;
  const int c = (idx / N) % C;
  float v = (y[idx] - mean[c]) * istd[c] * g[c] + bta[c];
  if (relu) v = fmaxf(v, 0.f);
  out[idx] = v;
}

// ---------------- conv 2x2 stride 2, bias ----------------
__global__ void conv2x2s2_k(const float* __restrict__ in, const float* __restrict__ wgt,
                            const float* __restrict__ bias, float* __restrict__ out) {
  const int b = blockIdx.z, co = blockIdx.y;
  const int p = blockIdx.x * 256 + threadIdx.x;
  __shared__ float wsm[C * 4];
  for (int i = threadIdx.x; i < C * 4; i += 256) wsm[i] = wgt[co * C * 4 + i];
  __syncthreads();
  if (p >= NQ) return;
  const int oh = p / 40, ow = p - oh * 40;
  const float* inb = in + (size_t)b * C * N + (oh * 2) * W + ow * 2;
  float acc = bias[co];
  for (int ci = 0; ci < C; ++ci) {
    const float* xp = inb + ci * N;
    const float* wp = wsm + ci * 4;
    acc = fmaf(wp[0], xp[0], acc);
    acc = fmaf(wp[1], xp[1], acc);
    acc = fmaf(wp[2], xp[W], acc);
    acc = fmaf(wp[3], xp[W + 1], acc);
  }
  out[((size_t)b * C + co) * NQ + p] = acc;
}

// ---------------- conv 1x1, bias, fp32 out ----------------
__global__ void conv1x1_k(const float* __restrict__ in, const float* __restrict__ wgt,
                          const float* __restrict__ bias, float* __restrict__ out, int Cout) {
  const int b = blockIdx.z, co = blockIdx.y;
  const int p = blockIdx.x * 256 + threadIdx.x;
  __shared__ float wsm[C];
  if (threadIdx.x < C) wsm[threadIdx.x] = wgt[co * C + threadIdx.x];
  __syncthreads();
  float acc = bias[co];
  const float* inb = in + (size_t)b * C * N + p;
#pragma unroll 8
  for (int ci = 0; ci < C; ++ci) acc = fmaf(wsm[ci], inb[ci * N], acc);
  out[((size_t)b * Cout + co) * N + p] = acc;
}

// ---------------- conv 1x1, bias, bf16 out (for PAM value) ----------------
__global__ void conv1x1b_k(const float* __restrict__ in, const float* __restrict__ wgt,
                           const float* __restrict__ bias, unsigned short* __restrict__ out) {
  const int b = blockIdx.z, co = blockIdx.y;
  const int p = blockIdx.x * 256 + threadIdx.x;
  __shared__ float wsm[C];
  if (threadIdx.x < C) wsm[threadIdx.x] = wgt[co * C + threadIdx.x];
  __syncthreads();
  float acc = bias[co];
  const float* inb = in + (size_t)b * C * N + p;
#pragma unroll 8
  for (int ci = 0; ci < C; ++ci) acc = fmaf(wsm[ci], inb[ci * N], acc);
  out[((size_t)b * C + co) * N + p] = f2bf(acc);
}

// ---------------- CAM: energy + (max - e) softmax fused ----------------
__global__ void cam_attn_k(const float* __restrict__ q, const float* __restrict__ k,
                           float* __restrict__ attn) {
  const int b = blockIdx.y, c = blockIdx.x, d = threadIdx.x;  // block = 64 threads
  const float* qp = q + ((size_t)b * C + c) * NQ;
  const float* kp = k + ((size_t)b * C + d) * NQ;
  float s0 = 0.f, s1 = 0.f, s2 = 0.f, s3 = 0.f;
  for (int n = 0; n < NQ; n += 4) {
    s0 = fmaf(qp[n + 0], kp[n + 0], s0);
    s1 = fmaf(qp[n + 1], kp[n + 1], s1);
    s2 = fmaf(qp[n + 2], kp[n + 2], s2);
    s3 = fmaf(qp[n + 3], kp[n + 3], s3);
  }
  const float e = (s0 + s1) + (s2 + s3);
  float rmax = e;
#pragma unroll
  for (int m = 1; m < 64; m <<= 1) rmax = fmaxf(rmax, __shfl_xor(rmax, m));
  const float e2 = rmax - e;
  float m2 = e2;
#pragma unroll
  for (int m = 1; m < 64; m <<= 1) m2 = fmaxf(m2, __shfl_xor(m2, m));
  const float pexp = __expf(e2 - m2);
  float ssum = pexp;
#pragma unroll
  for (int m = 1; m < 64; m <<= 1) ssum += __shfl_xor(ssum, m);
  attn[((size_t)b * C + c) * C + d] = pexp / ssum;
}

// ---------------- PAM flash: online softmax + bf16 MFMA PV, m-split partials ----------------
// out partial: scp[mc][b][c][n] (unnormalized), Mp/Lp[mc][b][n] (chunk max / sum-exp)
__global__ __launch_bounds__(256) void pam_flash_k(
    const float* __restrict__ pq, const float* __restrict__ pk,
    const unsigned short* __restrict__ pvh,
    float* __restrict__ scp, float* __restrict__ Mp, float* __restrict__ Lp) {
  const int b = blockIdx.z, mc = blockIdx.y, nt = blockIdx.x;
  const int t = threadIdx.x;
  const int wv = t >> 6, lane = t & 63;
  const int ln15 = lane & 15, quad = lane >> 4;
  const int n_g = nt * 64 + wv * 16 + ln15;   // this lane's n (column)
  const int m0c = mc * MCH;

  __shared__ float pk_s[C8][MCH];  // 25.6 KB
  for (int i = t; i < C8 * MCH; i += 256) {
    const int j = i / MCH, m = i - j * MCH;
    pk_s[j][m] = pk[((size_t)b * C8 + j) * N + m0c + m];
  }

  float qreg[8];
#pragma unroll
  for (int j = 0; j < 8; ++j) qreg[j] = pq[((size_t)b * C8 + j) * N + n_g];

  f32x4 acc[4];
#pragma unroll
  for (int i = 0; i < 4; ++i) acc[i] = (f32x4){0.f, 0.f, 0.f, 0.f};
  float m_run = -1e30f, l_run = 0.f;

  __syncthreads();

  const unsigned short* pvb = pvh + (size_t)b * C * N;
  for (int mt = 0; mt < MCH / 32; ++mt) {
    const int mloc = mt * 32;
    const int mg = m0c + mloc + quad * 8;
    // A-fragments: pv[c][mg..mg+8), c = ln15 + 16*t4  (bf16, 16B each, L2-resident)
    U4H8 afr[4];
#pragma unroll
    for (int t4 = 0; t4 < 4; ++t4)
      afr[t4].u = *(const uint4*)&pvb[(size_t)(ln15 + 16 * t4) * N + mg];
    // scores for this lane's n, m = mloc + quad*8 + i
    float s[8] = {0.f, 0.f, 0.f, 0.f, 0.f, 0.f, 0.f, 0.f};
#pragma unroll
    for (int j = 0; j < 8; ++j) {
      const float4 k0 = *(const float4*)&pk_s[j][mloc + quad * 8];
      const float4 k1 = *(const float4*)&pk_s[j][mloc + quad * 8 + 4];
      const float qj = qreg[j];
      s[0] = fmaf(qj, k0.x, s[0]); s[1] = fmaf(qj, k0.y, s[1]);
      s[2] = fmaf(qj, k0.z, s[2]); s[3] = fmaf(qj, k0.w, s[3]);
      s[4] = fmaf(qj, k1.x, s[4]); s[5] = fmaf(qj, k1.y, s[5]);
      s[6] = fmaf(qj, k1.z, s[6]); s[7] = fmaf(qj, k1.w, s[7]);
    }
    // online softmax (per-n, shared across the 4 quads owning this n)
    float tmax = fmaxf(fmaxf(fmaxf(s[0], s[1]), fmaxf(s[2], s[3])),
                       fmaxf(fmaxf(s[4], s[5]), fmaxf(s[6], s[7])));
    tmax = fmaxf(tmax, __shfl_xor(tmax, 16));
    tmax = fmaxf(tmax, __shfl_xor(tmax, 32));
    const float m_new = fmaxf(m_run, tmax);
    const float alpha = __expf(m_run - m_new);
    H8U wb;
    float lsum = 0.f;
#pragma unroll
    for (int i = 0; i < 8; ++i) {
      const float wv_ = __expf(s[i] - m_new);
      lsum += wv_;
      wb.s[i] = f2bf(wv_);
    }
    l_run = fmaf(l_run, alpha, lsum);
    m_run = m_new;
#pragma unroll
    for (int t4 = 0; t4 < 4; ++t4) {
      acc[t4].x *= alpha; acc[t4].y *= alpha; acc[t4].z *= alpha; acc[t4].w *= alpha;
      acc[t4] = __builtin_amdgcn_mfma_f32_16x16x32_bf16(afr[t4].h, wb.h, acc[t4], 0, 0, 0);
    }
  }

  // reduce l across the 4 quads sharing this n
  float lt = l_run;
  lt += __shfl_xor(lt, 16);
  lt += __shfl_xor(lt, 32);
  if (lane < 16) {
    const size_t si = (size_t)mc * (B * N) + (size_t)b * N + n_g;
    Mp[si] = m_run;
    Lp[si] = lt;
  }
  float* outp = scp + ((size_t)(mc * B + b)) * C * N;
#pragma unroll
  for (int t4 = 0; t4 < 4; ++t4) {
    outp[(size_t)(t4 * 16 + quad * 4 + 0) * N + n_g] = acc[t4].x;
    outp[(size_t)(t4 * 16 + quad * 4 + 1) * N + n_g] = acc[t4].y;
    outp[(size_t)(t4 * 16 + quad * 4 + 2) * N + n_g] = acc[t4].z;
    outp[(size_t)(t4 * 16 + quad * 4 + 3) * N + n_g] = acc[t4].w;
  }
}

// ---------------- PAM merge: per-n combine factors f_s = exp(M_s - M)/L ----------------
__global__ void pam_merge2_k(const float* __restrict__ Mp, const float* __restrict__ Lp,
                             float* __restrict__ Fs) {
  const int ng = blockIdx.x * 256 + threadIdx.x;  // < B*N
  float M = -1e30f;
#pragma unroll
  for (int s = 0; s < SAP; ++s) M = fmaxf(M, Mp[(size_t)s * (B * N) + ng]);
  float L = 0.f;
#pragma unroll
  for (int s = 0; s < SAP; ++s)
    L = fmaf(Lp[(size_t)s * (B * N) + ng], __expf(Mp[(size_t)s * (B * N) + ng] - M), L);
  const float invL = 1.f / L;
#pragma unroll
  for (int s = 0; s < SAP; ++s)
    Fs[(size_t)s * (B * N) + ng] = __expf(Mp[(size_t)s * (B * N) + ng] - M) * invL;
}

// ---------------- combine: feat1 + g1*(attn_c @ v) + g2*Σ_s scp_s*f_s ----------------
__global__ void combine_k(const float* __restrict__ attn, const float* __restrict__ v,
                          const float* __restrict__ feat1, const float* __restrict__ scp,
                          const float* __restrict__ Fs,
                          const float* __restrict__ g1, const float* __restrict__ g2,
                          float* __restrict__ fsum) {
  const int b = blockIdx.z, c = blockIdx.y;
  const int p = blockIdx.x * 256 + threadIdx.x;
  __shared__ float as_[C];
  if (threadIdx.x < C) as_[threadIdx.x] = attn[((size_t)b * C + c) * C + threadIdx.x];
  __syncthreads();
  float acc = 0.f;
  const float* vb = v + (size_t)b * C * N + p;
#pragma unroll 8
  for (int d = 0; d < C; ++d) acc = fmaf(as_[d], vb[d * N], acc);
  const size_t idx = ((size_t)b * C + c) * N + p;
  float sc = 0.f;
#pragma unroll
  for (int s = 0; s < SAP; ++s)
    sc = fmaf(scp[(size_t)s * B * C * N + idx], Fs[(size_t)s * (B * N) + b * N + p], sc);
  fsum[idx] = fmaf(g1[0], acc, fmaf(g2[0], sc, feat1[idx]));
}

}  // namespace

extern "C" void kernel_launch(void* const* d_in, const int* in_sizes, int n_in,
                              void* d_out, int out_size, void* d_ws, size_t ws_size,
                              hipStream_t stream) {
  (void)in_sizes; (void)n_in; (void)out_size; (void)ws_size;
  const float* x    = (const float*)d_in[0];
  const float* Wc   = (const float*)d_in[1];
  const float* bn1g = (const float*)d_in[2];
  const float* bn1b = (const float*)d_in[3];
  const float* cqw  = (const float*)d_in[4];
  const float* cqb  = (const float*)d_in[5];
  const float* ckw  = (const float*)d_in[6];
  const float* ckb  = (const float*)d_in[7];
  const float* cvw  = (const float*)d_in[8];
  const float* cvb  = (const float*)d_in[9];
  const float* pqw  = (const float*)d_in[10];
  const float* pqb  = (const float*)d_in[11];
  const float* pkw  = (const float*)d_in[12];
  const float* pkb  = (const float*)d_in[13];
  const float* pvw  = (const float*)d_in[14];
  const float* pvb  = (const float*)d_in[15];
  const float* g1   = (const float*)d_in[16];
  const float* g2   = (const float*)d_in[17];
  const float* bn2g = (const float*)d_in[18];
  const float* bn2b = (const float*)d_in[19];
  const float* Wd   = (const float*)d_in[20];
  const float* bn3g = (const float*)d_in[21];
  const float* bn3b = (const float*)d_in[22];
  float* out = (float*)d_out;

  float* wsp = (float*)d_ws;
  size_t off = 0;
  auto alloc = [&](size_t nel) { float* p = wsp + off; off += nel; return p; };
  float* feat1 = alloc((size_t)B * C * N);
  float* y1    = alloc((size_t)B * C * N);
  float* qb    = alloc((size_t)B * C * NQ);
  float* kb    = alloc((size_t)B * C * NQ);
  float* vb    = alloc((size_t)B * C * N);
  float* attn  = alloc((size_t)B * C * C);
  float* pq    = alloc((size_t)B * C8 * N);
  float* pk    = alloc((size_t)B * C8 * N);
  unsigned short* pvh = (unsigned short*)alloc((size_t)B * C * N / 2);  // bf16
  float* scp   = alloc((size_t)SAP * B * C * N);
  float* Mp    = alloc((size_t)SAP * B * N);
  float* Lp    = alloc((size_t)SAP * B * N);
  float* Fs    = alloc((size_t)SAP * B * N);
  float* fsum  = alloc((size_t)B * C * N);
  float* x2    = alloc((size_t)B * C * N);
  float* y3    = alloc((size_t)B * C * N);
  float* mean1 = alloc(C); float* istd1 = alloc(C);
  float* mean2 = alloc(C); float* istd2 = alloc(C);
  float* mean3 = alloc(C); float* istd3 = alloc(C);

  // conv_c -> bn1 -> relu
  conv3x3_k<<<dim3(N / 256, C, B), 256, 0, stream>>>(x, Wc, y1);
  bn_stats_k<<<dim3(C), 256, 0, stream>>>(y1, mean1, istd1);
  bn_apply_k<<<dim3(B * C * N / 256), 256, 0, stream>>>(y1, mean1, istd1, bn1g, bn1b, feat1, 1);
  // CAM inputs
  conv2x2s2_k<<<dim3(7, C, B), 256, 0, stream>>>(feat1, cqw, cqb, qb);
  conv2x2s2_k<<<dim3(7, C, B), 256, 0, stream>>>(feat1, ckw, ckb, kb);
  conv1x1_k<<<dim3(N / 256, C, B), 256, 0, stream>>>(feat1, cvw, cvb, vb, C);
  // PAM inputs
  conv1x1_k<<<dim3(N / 256, C8, B), 256, 0, stream>>>(feat1, pqw, pqb, pq, C8);
  conv1x1_k<<<dim3(N / 256, C8, B), 256, 0, stream>>>(feat1, pkw, pkb, pk, C8);
  conv1x1b_k<<<dim3(N / 256, C, B), 256, 0, stream>>>(feat1, pvw, pvb, pvh);
  // CAM attention
  cam_attn_k<<<dim3(C, B), 64, 0, stream>>>(qb, kb, attn);
  // PAM flash attention (single pass) + merge
  pam_flash_k<<<dim3(N / 64, SAP, B), 256, 0, stream>>>(pq, pk, pvh, scp, Mp, Lp);
  pam_merge2_k<<<dim3(B * N / 256), 256, 0, stream>>>(Mp, Lp, Fs);
  // combine
  combine_k<<<dim3(N / 256, C, B), 256, 0, stream>>>(attn, vb, feat1, scp, Fs, g1, g2, fsum);
  // bn2 -> conv_d -> bn3 -> relu
  bn_stats_k<<<dim3(C), 256, 0, stream>>>(fsum, mean2, istd2);
  bn_apply_k<<<dim3(B * C * N / 256), 256, 0, stream>>>(fsum, mean2, istd2, bn2g, bn2b, x2, 0);
  conv3x3_k<<<dim3(N / 256, C, B), 256, 0, stream>>>(x2, Wd, y3);
  bn_stats_k<<<dim3(C), 256, 0, stream>>>(y3, mean3, istd3);
  bn_apply_k<<<dim3(B * C * N / 256), 256, 0, stream>>>(y3, mean3, istd3, bn3g, bn3b, out, 1);
}

// Round 3
// 373.298 us; speedup vs baseline: 2.5047x; 1.6856x over previous
//
#include <hip/hip_runtime.h>
#include <math.h>

namespace {

constexpr int B = 2, C = 64, H = 80, W = 80, N = H * W;  // N = 6400
constexpr int NQ = 1600;   // 40*40
constexpr int C8 = 8;
constexpr float EPS = 1e-5f;
constexpr int SAP = 8;           // pam flash m-chunks
constexpr int MCH = N / SAP;     // 800 m per chunk

typedef __attribute__((ext_vector_type(8))) short bf16x8;
typedef __attribute__((ext_vector_type(4))) float f32x4;

union U4H8 { uint4 u; bf16x8 h; };
union H8U { unsigned short s[8]; bf16x8 h; };

__device__ __forceinline__ unsigned short f2bf(float x) {
  unsigned u = __builtin_bit_cast(unsigned, x);
  u += 0x7fffu + ((u >> 16) & 1u);   // RNE (no NaN inputs here)
  return (unsigned short)(u >> 16);
}

// ---------------- NCHW fp32 -> NHWC bf16 transpose ----------------
__global__ void to_nhwc_k(const float* __restrict__ in, unsigned short* __restrict__ out) {
  const int idx = blockIdx.x * 256 + threadIdx.x;  // b*N+p
  const int b = idx / N, p = idx - b * N;
  const float* ip = in + (size_t)b * C * N + p;
#pragma unroll
  for (int j = 0; j < 8; ++j) {
    H8U v;
#pragma unroll
    for (int i = 0; i < 8; ++i) v.s[i] = f2bf(ip[(size_t)(j * 8 + i) * N]);
    *(uint4*)&out[(size_t)idx * C + j * 8] = *(uint4*)&v;
  }
}

// ---------------- OIHW fp32 -> [tap][co][ci] bf16 weight transform ----------------
__global__ void wxform_k(const float* __restrict__ w, unsigned short* __restrict__ wt) {
  for (int i = blockIdx.x * 256 + threadIdx.x; i < C * C * 9; i += gridDim.x * 256) {
    const int co = i / 576, rem = i - co * 576;
    const int ci = rem / 9, kk = rem - ci * 9;
    wt[(size_t)kk * (C * C) + co * C + ci] = f2bf(w[i]);
  }
}

// ---------------- conv 3x3 pad 1 via implicit-GEMM MFMA ----------------
// in_t: [b][p][ci] bf16; wt: [tap][co][ci] bf16; out: [b][co][p] fp32
__global__ __launch_bounds__(64) void conv3x3_mfma_k(
    const unsigned short* __restrict__ in_t, const unsigned short* __restrict__ wt,
    float* __restrict__ out) {
  const int b = blockIdx.y, tile = blockIdx.x;  // 400 tiles of 16 pixels (within-row)
  const int h = tile / 5, wbase = (tile - h * 5) * 16;
  const int lane = threadIdx.x, ln15 = lane & 15, quad = lane >> 4;
  const int w0 = wbase + ln15;
  const unsigned short* itb = in_t + (size_t)b * N * C;

  f32x4 acc[4];
#pragma unroll
  for (int i = 0; i < 4; ++i) acc[i] = (f32x4){0.f, 0.f, 0.f, 0.f};

#pragma unroll
  for (int dh = -1; dh <= 1; ++dh) {
    const int hh = h + dh;
    if ((unsigned)hh >= (unsigned)H) continue;  // wave-uniform
#pragma unroll
    for (int dw = -1; dw <= 1; ++dw) {
      const bool valid = (unsigned)(w0 + dw) < (unsigned)W;
      const int pp = hh * W + (valid ? w0 + dw : w0);
      const uint4* bp = (const uint4*)(itb + (size_t)pp * C);
      U4H8 b0, b1;
      b0.u = bp[quad];
      b1.u = bp[4 + quad];
      if (!valid) { b0.u = make_uint4(0, 0, 0, 0); b1.u = make_uint4(0, 0, 0, 0); }
      const int kk = (dh + 1) * 3 + (dw + 1);
      const uint4* wp = (const uint4*)(wt + (size_t)kk * (C * C));
#pragma unroll
      for (int t4 = 0; t4 < 4; ++t4) {
        U4H8 a0, a1;
        a0.u = wp[(t4 * 16 + ln15) * 8 + quad];
        a1.u = wp[(t4 * 16 + ln15) * 8 + 4 + quad];
        acc[t4] = __builtin_amdgcn_mfma_f32_16x16x32_bf16(a0.h, b0.h, acc[t4], 0, 0, 0);
        acc[t4] = __builtin_amdgcn_mfma_f32_16x16x32_bf16(a1.h, b1.h, acc[t4], 0, 0, 0);
      }
    }
  }
  const int p = h * W + w0;
  float* ob = out + (size_t)b * C * N + p;
#pragma unroll
  for (int t4 = 0; t4 < 4; ++t4) {
    const int co = t4 * 16 + quad * 4;
    ob[(size_t)(co + 0) * N] = acc[t4].x;
    ob[(size_t)(co + 1) * N] = acc[t4].y;
    ob[(size_t)(co + 2) * N] = acc[t4].z;
    ob[(size_t)(co + 3) * N] = acc[t4].w;
  }
}

// ---------------- BN batch stats ----------------
__global__ void bn_stats_k(const float* __restrict__ y, float* __restrict__ mean,
                           float* __restrict__ istd) {
  const int c = blockIdx.x;
  float s = 0.f, s2 = 0.f;
  for (int i = threadIdx.x; i < B * N; i += 256) {
    const int b = i / N, n = i - b * N;
    const float v = y[((size_t)b * C + c) * N + n];
    s += v;
    s2 = fmaf(v, v, s2);
  }
#pragma unroll
  for (int off = 1; off < 64; off <<= 1) {
    s += __shfl_xor(s, off);
    s2 += __shfl_xor(s2, off);
  }
  __shared__ float rs[4], rs2[4];
  const int wid = threadIdx.x >> 6, lid = threadIdx.x & 63;
  if (lid == 0) { rs[wid] = s; rs2[wid] = s2; }
  __syncthreads();
  if (threadIdx.x == 0) {
    float ts = rs[0] + rs[1] + rs[2] + rs[3];
    float t2 = rs2[0] + rs2[1] + rs2[2] + rs2[3];
    const float m = ts / (float)(B * N);
    const float var = t2 / (float)(B * N) - m * m;
    mean[c] = m;
    istd[c] = rsqrtf(var + EPS);
  }
}

// ---------------- BN apply (optional relu) ----------------
__global__ void bn_apply_k(const float* __restrict__ y, const float* __restrict__ mean,
                           const float* __restrict__ istd, const float* __restrict__ g,
                           const float* __restrict__ bta, float* __restrict__ out, int relu) {
  const int idx = blockIdx.x * 256 + threadIdx.x;
  const int c = (idx / N) % C;
  float v = (y[idx] - mean[c]) * istd[c] * g[c] + bta[c];
  if (relu) v = fmaxf(v, 0.f);
  out[idx] = v;
}

// ---------------- conv 2x2 stride 2, bias ----------------
__global__ void conv2x2s2_k(const float* __restrict__ in, const float* __restrict__ wgt,
                            const float* __restrict__ bias, float* __restrict__ out) {
  const int b = blockIdx.z, co = blockIdx.y;
  const int p = blockIdx.x * 256 + threadIdx.x;
  __shared__ float wsm[C * 4];
  for (int i = threadIdx.x; i < C * 4; i += 256) wsm[i] = wgt[co * C * 4 + i];
  __syncthreads();
  if (p >= NQ) return;
  const int oh = p / 40, ow = p - oh * 40;
  const float* inb = in + (size_t)b * C * N + (oh * 2) * W + ow * 2;
  float acc = bias[co];
  for (int ci = 0; ci < C; ++ci) {
    const float* xp = inb + ci * N;
    const float* wp = wsm + ci * 4;
    acc = fmaf(wp[0], xp[0], acc);
    acc = fmaf(wp[1], xp[1], acc);
    acc = fmaf(wp[2], xp[W], acc);
    acc = fmaf(wp[3], xp[W + 1], acc);
  }
  out[((size_t)b * C + co) * NQ + p] = acc;
}

// ---------------- conv 1x1, bias, fp32 out ----------------
__global__ void conv1x1_k(const float* __restrict__ in, const float* __restrict__ wgt,
                          const float* __restrict__ bias, float* __restrict__ out, int Cout) {
  const int b = blockIdx.z, co = blockIdx.y;
  const int p = blockIdx.x * 256 + threadIdx.x;
  __shared__ float wsm[C];
  if (threadIdx.x < C) wsm[threadIdx.x] = wgt[co * C + threadIdx.x];
  __syncthreads();
  float acc = bias[co];
  const float* inb = in + (size_t)b * C * N + p;
#pragma unroll 8
  for (int ci = 0; ci < C; ++ci) acc = fmaf(wsm[ci], inb[ci * N], acc);
  out[((size_t)b * Cout + co) * N + p] = acc;
}

// ---------------- conv 1x1, bias, bf16 out (for PAM value) ----------------
__global__ void conv1x1b_k(const float* __restrict__ in, const float* __restrict__ wgt,
                           const float* __restrict__ bias, unsigned short* __restrict__ out) {
  const int b = blockIdx.z, co = blockIdx.y;
  const int p = blockIdx.x * 256 + threadIdx.x;
  __shared__ float wsm[C];
  if (threadIdx.x < C) wsm[threadIdx.x] = wgt[co * C + threadIdx.x];
  __syncthreads();
  float acc = bias[co];
  const float* inb = in + (size_t)b * C * N + p;
#pragma unroll 8
  for (int ci = 0; ci < C; ++ci) acc = fmaf(wsm[ci], inb[ci * N], acc);
  out[((size_t)b * C + co) * N + p] = f2bf(acc);
}

// ---------------- CAM: energy + (max - e) softmax fused ----------------
__global__ void cam_attn_k(const float* __restrict__ q, const float* __restrict__ k,
                           float* __restrict__ attn) {
  const int b = blockIdx.y, c = blockIdx.x, d = threadIdx.x;  // block = 64 threads
  const float* qp = q + ((size_t)b * C + c) * NQ;
  const float* kp = k + ((size_t)b * C + d) * NQ;
  float s0 = 0.f, s1 = 0.f, s2 = 0.f, s3 = 0.f;
  for (int n = 0; n < NQ; n += 4) {
    s0 = fmaf(qp[n + 0], kp[n + 0], s0);
    s1 = fmaf(qp[n + 1], kp[n + 1], s1);
    s2 = fmaf(qp[n + 2], kp[n + 2], s2);
    s3 = fmaf(qp[n + 3], kp[n + 3], s3);
  }
  const float e = (s0 + s1) + (s2 + s3);
  float rmax = e;
#pragma unroll
  for (int m = 1; m < 64; m <<= 1) rmax = fmaxf(rmax, __shfl_xor(rmax, m));
  const float e2 = rmax - e;
  float m2 = e2;
#pragma unroll
  for (int m = 1; m < 64; m <<= 1) m2 = fmaxf(m2, __shfl_xor(m2, m));
  const float pexp = __expf(e2 - m2);
  float ssum = pexp;
#pragma unroll
  for (int m = 1; m < 64; m <<= 1) ssum += __shfl_xor(ssum, m);
  attn[((size_t)b * C + c) * C + d] = pexp / ssum;
}

// ---------------- PAM flash: online softmax + bf16 MFMA PV, m-split partials ----------------
__global__ __launch_bounds__(256) void pam_flash_k(
    const float* __restrict__ pq, const float* __restrict__ pk,
    const unsigned short* __restrict__ pvh,
    float* __restrict__ scp, float* __restrict__ Mp, float* __restrict__ Lp) {
  const int b = blockIdx.z, mc = blockIdx.y, nt = blockIdx.x;
  const int t = threadIdx.x;
  const int wv = t >> 6, lane = t & 63;
  const int ln15 = lane & 15, quad = lane >> 4;
  const int n_g = nt * 64 + wv * 16 + ln15;
  const int m0c = mc * MCH;

  __shared__ float pk_s[C8][MCH];  // 25.6 KB
  for (int i = t; i < C8 * MCH; i += 256) {
    const int j = i / MCH, m = i - j * MCH;
    pk_s[j][m] = pk[((size_t)b * C8 + j) * N + m0c + m];
  }

  float qreg[8];
#pragma unroll
  for (int j = 0; j < 8; ++j) qreg[j] = pq[((size_t)b * C8 + j) * N + n_g];

  f32x4 acc[4];
#pragma unroll
  for (int i = 0; i < 4; ++i) acc[i] = (f32x4){0.f, 0.f, 0.f, 0.f};
  float m_run = -1e30f, l_run = 0.f;

  __syncthreads();

  const unsigned short* pvb = pvh + (size_t)b * C * N;
  for (int mt = 0; mt < MCH / 32; ++mt) {
    const int mloc = mt * 32;
    const int mg = m0c + mloc + quad * 8;
    U4H8 afr[4];
#pragma unroll
    for (int t4 = 0; t4 < 4; ++t4)
      afr[t4].u = *(const uint4*)&pvb[(size_t)(ln15 + 16 * t4) * N + mg];
    float s[8] = {0.f, 0.f, 0.f, 0.f, 0.f, 0.f, 0.f, 0.f};
#pragma unroll
    for (int j = 0; j < 8; ++j) {
      const float4 k0 = *(const float4*)&pk_s[j][mloc + quad * 8];
      const float4 k1 = *(const float4*)&pk_s[j][mloc + quad * 8 + 4];
      const float qj = qreg[j];
      s[0] = fmaf(qj, k0.x, s[0]); s[1] = fmaf(qj, k0.y, s[1]);
      s[2] = fmaf(qj, k0.z, s[2]); s[3] = fmaf(qj, k0.w, s[3]);
      s[4] = fmaf(qj, k1.x, s[4]); s[5] = fmaf(qj, k1.y, s[5]);
      s[6] = fmaf(qj, k1.z, s[6]); s[7] = fmaf(qj, k1.w, s[7]);
    }
    float tmax = fmaxf(fmaxf(fmaxf(s[0], s[1]), fmaxf(s[2], s[3])),
                       fmaxf(fmaxf(s[4], s[5]), fmaxf(s[6], s[7])));
    tmax = fmaxf(tmax, __shfl_xor(tmax, 16));
    tmax = fmaxf(tmax, __shfl_xor(tmax, 32));
    const float m_new = fmaxf(m_run, tmax);
    const float alpha = __expf(m_run - m_new);
    H8U wb;
    float lsum = 0.f;
#pragma unroll
    for (int i = 0; i < 8; ++i) {
      const float wv_ = __expf(s[i] - m_new);
      lsum += wv_;
      wb.s[i] = f2bf(wv_);
    }
    l_run = fmaf(l_run, alpha, lsum);
    m_run = m_new;
#pragma unroll
    for (int t4 = 0; t4 < 4; ++t4) {
      acc[t4].x *= alpha; acc[t4].y *= alpha; acc[t4].z *= alpha; acc[t4].w *= alpha;
      acc[t4] = __builtin_amdgcn_mfma_f32_16x16x32_bf16(afr[t4].h, wb.h, acc[t4], 0, 0, 0);
    }
  }

  float lt = l_run;
  lt += __shfl_xor(lt, 16);
  lt += __shfl_xor(lt, 32);
  if (lane < 16) {
    const size_t si = (size_t)mc * (B * N) + (size_t)b * N + n_g;
    Mp[si] = m_run;
    Lp[si] = lt;
  }
  float* outp = scp + ((size_t)(mc * B + b)) * C * N;
#pragma unroll
  for (int t4 = 0; t4 < 4; ++t4) {
    outp[(size_t)(t4 * 16 + quad * 4 + 0) * N + n_g] = acc[t4].x;
    outp[(size_t)(t4 * 16 + quad * 4 + 1) * N + n_g] = acc[t4].y;
    outp[(size_t)(t4 * 16 + quad * 4 + 2) * N + n_g] = acc[t4].z;
    outp[(size_t)(t4 * 16 + quad * 4 + 3) * N + n_g] = acc[t4].w;
  }
}

// ---------------- PAM merge: per-n combine factors f_s = exp(M_s - M)/L ----------------
__global__ void pam_merge2_k(const float* __restrict__ Mp, const float* __restrict__ Lp,
                             float* __restrict__ Fs) {
  const int ng = blockIdx.x * 256 + threadIdx.x;
  float M = -1e30f;
#pragma unroll
  for (int s = 0; s < SAP; ++s) M = fmaxf(M, Mp[(size_t)s * (B * N) + ng]);
  float L = 0.f;
#pragma unroll
  for (int s = 0; s < SAP; ++s)
    L = fmaf(Lp[(size_t)s * (B * N) + ng], __expf(Mp[(size_t)s * (B * N) + ng] - M), L);
  const float invL = 1.f / L;
#pragma unroll
  for (int s = 0; s < SAP; ++s)
    Fs[(size_t)s * (B * N) + ng] = __expf(Mp[(size_t)s * (B * N) + ng] - M) * invL;
}

// ---------------- combine: feat1 + g1*(attn_c @ v) + g2*Σ_s scp_s*f_s ----------------
__global__ void combine_k(const float* __restrict__ attn, const float* __restrict__ v,
                          const float* __restrict__ feat1, const float* __restrict__ scp,
                          const float* __restrict__ Fs,
                          const float* __restrict__ g1, const float* __restrict__ g2,
                          float* __restrict__ fsum) {
  const int b = blockIdx.z, c = blockIdx.y;
  const int p = blockIdx.x * 256 + threadIdx.x;
  __shared__ float as_[C];
  if (threadIdx.x < C) as_[threadIdx.x] = attn[((size_t)b * C + c) * C + threadIdx.x];
  __syncthreads();
  float acc = 0.f;
  const float* vb = v + (size_t)b * C * N + p;
#pragma unroll 8
  for (int d = 0; d < C; ++d) acc = fmaf(as_[d], vb[d * N], acc);
  const size_t idx = ((size_t)b * C + c) * N + p;
  float sc = 0.f;
#pragma unroll
  for (int s = 0; s < SAP; ++s)
    sc = fmaf(scp[(size_t)s * B * C * N + idx], Fs[(size_t)s * (B * N) + b * N + p], sc);
  fsum[idx] = fmaf(g1[0], acc, fmaf(g2[0], sc, feat1[idx]));
}

}  // namespace

extern "C" void kernel_launch(void* const* d_in, const int* in_sizes, int n_in,
                              void* d_out, int out_size, void* d_ws, size_t ws_size,
                              hipStream_t stream) {
  (void)in_sizes; (void)n_in; (void)out_size; (void)ws_size;
  const float* x    = (const float*)d_in[0];
  const float* Wc   = (const float*)d_in[1];
  const float* bn1g = (const float*)d_in[2];
  const float* bn1b = (const float*)d_in[3];
  const float* cqw  = (const float*)d_in[4];
  const float* cqb  = (const float*)d_in[5];
  const float* ckw  = (const float*)d_in[6];
  const float* ckb  = (const float*)d_in[7];
  const float* cvw  = (const float*)d_in[8];
  const float* cvb  = (const float*)d_in[9];
  const float* pqw  = (const float*)d_in[10];
  const float* pqb  = (const float*)d_in[11];
  const float* pkw  = (const float*)d_in[12];
  const float* pkb  = (const float*)d_in[13];
  const float* pvw  = (const float*)d_in[14];
  const float* pvb  = (const float*)d_in[15];
  const float* g1   = (const float*)d_in[16];
  const float* g2   = (const float*)d_in[17];
  const float* bn2g = (const float*)d_in[18];
  const float* bn2b = (const float*)d_in[19];
  const float* Wd   = (const float*)d_in[20];
  const float* bn3g = (const float*)d_in[21];
  const float* bn3b = (const float*)d_in[22];
  float* out = (float*)d_out;

  float* wsp = (float*)d_ws;
  size_t off = 0;
  auto alloc = [&](size_t nel) { float* p = wsp + off; off += nel; return p; };
  float* feat1 = alloc((size_t)B * C * N);
  float* y1    = alloc((size_t)B * C * N);
  float* qb    = alloc((size_t)B * C * NQ);
  float* kb    = alloc((size_t)B * C * NQ);
  float* vb    = alloc((size_t)B * C * N);
  float* attn  = alloc((size_t)B * C * C);
  float* pq    = alloc((size_t)B * C8 * N);
  float* pk    = alloc((size_t)B * C8 * N);
  unsigned short* pvh = (unsigned short*)alloc((size_t)B * C * N / 2);
  float* scp   = alloc((size_t)SAP * B * C * N);
  float* Mp    = alloc((size_t)SAP * B * N);
  float* Lp    = alloc((size_t)SAP * B * N);
  float* Fs    = alloc((size_t)SAP * B * N);
  float* fsum  = alloc((size_t)B * C * N);
  float* x2    = alloc((size_t)B * C * N);
  float* y3    = alloc((size_t)B * C * N);
  unsigned short* xt  = (unsigned short*)alloc((size_t)B * N * C / 2);
  unsigned short* x2t = (unsigned short*)alloc((size_t)B * N * C / 2);
  unsigned short* w9c = (unsigned short*)alloc((size_t)9 * C * C / 2);
  unsigned short* w9d = (unsigned short*)alloc((size_t)9 * C * C / 2);
  float* mean1 = alloc(C); float* istd1 = alloc(C);
  float* mean2 = alloc(C); float* istd2 = alloc(C);
  float* mean3 = alloc(C); float* istd3 = alloc(C);

  // weight transforms (independent)
  wxform_k<<<dim3(36), 256, 0, stream>>>(Wc, w9c);
  wxform_k<<<dim3(36), 256, 0, stream>>>(Wd, w9d);
  // conv_c -> bn1 -> relu
  to_nhwc_k<<<dim3(B * N / 256), 256, 0, stream>>>(x, xt);
  conv3x3_mfma_k<<<dim3(N / 16, B), 64, 0, stream>>>(xt, w9c, y1);
  bn_stats_k<<<dim3(C), 256, 0, stream>>>(y1, mean1, istd1);
  bn_apply_k<<<dim3(B * C * N / 256), 256, 0, stream>>>(y1, mean1, istd1, bn1g, bn1b, feat1, 1);
  // CAM inputs
  conv2x2s2_k<<<dim3(7, C, B), 256, 0, stream>>>(feat1, cqw, cqb, qb);
  conv2x2s2_k<<<dim3(7, C, B), 256, 0, stream>>>(feat1, ckw, ckb, kb);
  conv1x1_k<<<dim3(N / 256, C, B), 256, 0, stream>>>(feat1, cvw, cvb, vb, C);
  // PAM inputs
  conv1x1_k<<<dim3(N / 256, C8, B), 256, 0, stream>>>(feat1, pqw, pqb, pq, C8);
  conv1x1_k<<<dim3(N / 256, C8, B), 256, 0, stream>>>(feat1, pkw, pkb, pk, C8);
  conv1x1b_k<<<dim3(N / 256, C, B), 256, 0, stream>>>(feat1, pvw, pvb, pvh);
  // CAM attention
  cam_attn_k<<<dim3(C, B), 64, 0, stream>>>(qb, kb, attn);
  // PAM flash attention (single pass) + merge
  pam_flash_k<<<dim3(N / 64, SAP, B), 256, 0, stream>>>(pq, pk, pvh, scp, Mp, Lp);
  pam_merge2_k<<<dim3(B * N / 256), 256, 0, stream>>>(Mp, Lp, Fs);
  // combine
  combine_k<<<dim3(N / 256, C, B), 256, 0, stream>>>(attn, vb, feat1, scp, Fs, g1, g2, fsum);
  // bn2 -> conv_d -> bn3 -> relu
  bn_stats_k<<<dim3(C), 256, 0, stream>>>(fsum, mean2, istd2);
  bn_apply_k<<<dim3(B * C * N / 256), 256, 0, stream>>>(fsum, mean2, istd2, bn2g, bn2b, x2, 0);
  to_nhwc_k<<<dim3(B * N / 256), 256, 0, stream>>>(x2, x2t);
  conv3x3_mfma_k<<<dim3(N / 16, B), 64, 0, stream>>>(x2t, w9d, y3);
  bn_stats_k<<<dim3(C), 256, 0, stream>>>(y3, mean3, istd3);
  bn_apply_k<<<dim3(B * C * N / 256), 256, 0, stream>>>(y3, mean3, istd3, bn3g, bn3b, out, 1);
}

// Round 4
// 331.298 us; speedup vs baseline: 2.8223x; 1.1268x over previous
//
#include <hip/hip_runtime.h>
#include <hip/hip_bf16.h>
#include <math.h>

namespace {

constexpr int B = 2, C = 64, H = 80, W = 80, N = H * W;  // N = 6400
constexpr int NQ = 1600;   // 40*40
constexpr int C8 = 8;
constexpr float EPS = 1e-5f;
constexpr int SAP = 8;           // pam flash m-chunks
constexpr int MCH = N / SAP;     // 800 m per chunk

typedef __attribute__((ext_vector_type(8))) short bf16x8;
typedef __attribute__((ext_vector_type(4))) float f32x4;

union U4H8 { uint4 u; bf16x8 h; };
union H8U { unsigned short s[8]; bf16x8 h; };
union WBU { __hip_bfloat162 h2[4]; bf16x8 h; };

__device__ __forceinline__ unsigned short f2bf(float x) {
  unsigned u = __builtin_bit_cast(unsigned, x);
  u += 0x7fffu + ((u >> 16) & 1u);   // RNE (no NaN inputs here)
  return (unsigned short)(u >> 16);
}

// ---------------- NCHW fp32 -> NHWC bf16 transpose ----------------
__global__ void to_nhwc_k(const float* __restrict__ in, unsigned short* __restrict__ out) {
  const int idx = blockIdx.x * 256 + threadIdx.x;  // b*N+p
  const int b = idx / N, p = idx - b * N;
  const float* ip = in + (size_t)b * C * N + p;
#pragma unroll
  for (int j = 0; j < 8; ++j) {
    H8U v;
#pragma unroll
    for (int i = 0; i < 8; ++i) v.s[i] = f2bf(ip[(size_t)(j * 8 + i) * N]);
    *(uint4*)&out[(size_t)idx * C + j * 8] = *(uint4*)&v;
  }
}

// ---------------- OIHW fp32 -> [tap][co][ci] bf16 weight transform ----------------
__global__ void wxform_k(const float* __restrict__ w, unsigned short* __restrict__ wt) {
  for (int i = blockIdx.x * 256 + threadIdx.x; i < C * C * 9; i += gridDim.x * 256) {
    const int co = i / 576, rem = i - co * 576;
    const int ci = rem / 9, kk = rem - ci * 9;
    wt[(size_t)kk * (C * C) + co * C + ci] = f2bf(w[i]);
  }
}

// ---------------- conv 3x3 pad 1 via implicit-GEMM MFMA ----------------
__global__ __launch_bounds__(64) void conv3x3_mfma_k(
    const unsigned short* __restrict__ in_t, const unsigned short* __restrict__ wt,
    float* __restrict__ out) {
  const int b = blockIdx.y, tile = blockIdx.x;  // 400 tiles of 16 pixels (within-row)
  const int h = tile / 5, wbase = (tile - h * 5) * 16;
  const int lane = threadIdx.x, ln15 = lane & 15, quad = lane >> 4;
  const int w0 = wbase + ln15;
  const unsigned short* itb = in_t + (size_t)b * N * C;

  f32x4 acc[4];
#pragma unroll
  for (int i = 0; i < 4; ++i) acc[i] = (f32x4){0.f, 0.f, 0.f, 0.f};

#pragma unroll
  for (int dh = -1; dh <= 1; ++dh) {
    const int hh = h + dh;
    if ((unsigned)hh >= (unsigned)H) continue;  // wave-uniform
#pragma unroll
    for (int dw = -1; dw <= 1; ++dw) {
      const bool valid = (unsigned)(w0 + dw) < (unsigned)W;
      const int pp = hh * W + (valid ? w0 + dw : w0);
      const uint4* bp = (const uint4*)(itb + (size_t)pp * C);
      U4H8 b0, b1;
      b0.u = bp[quad];
      b1.u = bp[4 + quad];
      if (!valid) { b0.u = make_uint4(0, 0, 0, 0); b1.u = make_uint4(0, 0, 0, 0); }
      const int kk = (dh + 1) * 3 + (dw + 1);
      const uint4* wp = (const uint4*)(wt + (size_t)kk * (C * C));
#pragma unroll
      for (int t4 = 0; t4 < 4; ++t4) {
        U4H8 a0, a1;
        a0.u = wp[(t4 * 16 + ln15) * 8 + quad];
        a1.u = wp[(t4 * 16 + ln15) * 8 + 4 + quad];
        acc[t4] = __builtin_amdgcn_mfma_f32_16x16x32_bf16(a0.h, b0.h, acc[t4], 0, 0, 0);
        acc[t4] = __builtin_amdgcn_mfma_f32_16x16x32_bf16(a1.h, b1.h, acc[t4], 0, 0, 0);
      }
    }
  }
  const int p = h * W + w0;
  float* ob = out + (size_t)b * C * N + p;
#pragma unroll
  for (int t4 = 0; t4 < 4; ++t4) {
    const int co = t4 * 16 + quad * 4;
    ob[(size_t)(co + 0) * N] = acc[t4].x;
    ob[(size_t)(co + 1) * N] = acc[t4].y;
    ob[(size_t)(co + 2) * N] = acc[t4].z;
    ob[(size_t)(co + 3) * N] = acc[t4].w;
  }
}

// ---------------- BN batch stats (1024-thread blocks) ----------------
__global__ __launch_bounds__(1024) void bn_stats_k(const float* __restrict__ y,
                                                   float* __restrict__ mean,
                                                   float* __restrict__ istd) {
  const int c = blockIdx.x;
  float s = 0.f, s2 = 0.f;
  for (int i = threadIdx.x; i < B * N; i += 1024) {
    const int b = i / N, n = i - b * N;
    const float v = y[((size_t)b * C + c) * N + n];
    s += v;
    s2 = fmaf(v, v, s2);
  }
#pragma unroll
  for (int off = 1; off < 64; off <<= 1) {
    s += __shfl_xor(s, off);
    s2 += __shfl_xor(s2, off);
  }
  __shared__ float rs[16], rs2[16];
  const int wid = threadIdx.x >> 6, lid = threadIdx.x & 63;
  if (lid == 0) { rs[wid] = s; rs2[wid] = s2; }
  __syncthreads();
  if (threadIdx.x == 0) {
    float ts = 0.f, t2 = 0.f;
#pragma unroll
    for (int i = 0; i < 16; ++i) { ts += rs[i]; t2 += rs2[i]; }
    const float m = ts / (float)(B * N);
    const float var = t2 / (float)(B * N) - m * m;
    mean[c] = m;
    istd[c] = rsqrtf(var + EPS);
  }
}

// ---------------- BN apply (optional relu) ----------------
__global__ void bn_apply_k(const float* __restrict__ y, const float* __restrict__ mean,
                           const float* __restrict__ istd, const float* __restrict__ g,
                           const float* __restrict__ bta, float* __restrict__ out, int relu) {
  const int idx = blockIdx.x * 256 + threadIdx.x;
  const int c = (idx / N) % C;
  float v = (y[idx] - mean[c]) * istd[c] * g[c] + bta[c];
  if (relu) v = fmaxf(v, 0.f);
  out[idx] = v;
}

// ---------------- BN2 apply + NHWC bf16 (feeds conv_d) ----------------
__global__ void bn2_nhwc_k(const float* __restrict__ fsum, const float* __restrict__ mean,
                           const float* __restrict__ istd, const float* __restrict__ g,
                           const float* __restrict__ bt, unsigned short* __restrict__ out) {
  __shared__ float sc_s[C], sh_s[C];
  if (threadIdx.x < C) {
    const int c = threadIdx.x;
    const float sc = istd[c] * g[c];
    sc_s[c] = sc;
    sh_s[c] = bt[c] - mean[c] * sc;
  }
  __syncthreads();
  const int idx = blockIdx.x * 256 + threadIdx.x;  // b*N+p
  const int b = idx / N, p = idx - b * N;
  const float* ip = fsum + (size_t)b * C * N + p;
#pragma unroll
  for (int j = 0; j < 8; ++j) {
    H8U v;
#pragma unroll
    for (int i = 0; i < 8; ++i) {
      const int c = j * 8 + i;
      v.s[i] = f2bf(fmaf(ip[(size_t)c * N], sc_s[c], sh_s[c]));
    }
    *(uint4*)&out[(size_t)idx * C + j * 8] = *(uint4*)&v;
  }
}

// ---------------- conv 2x2 stride 2, bias, q&k in one launch, transposed out ----------------
__global__ void conv2x2T_k(const float* __restrict__ in,
                           const float* __restrict__ cqw, const float* __restrict__ cqb,
                           const float* __restrict__ ckw, const float* __restrict__ ckb,
                           float* __restrict__ qT, float* __restrict__ kT) {
  const int z = blockIdx.z, b = z >> 1, sel = z & 1;
  const float* wgt = sel ? ckw : cqw;
  const float* bias = sel ? ckb : cqb;
  float* outT = sel ? kT : qT;
  const int co = blockIdx.y;
  const int p = blockIdx.x * 256 + threadIdx.x;
  __shared__ float wsm[C * 4];
  for (int i = threadIdx.x; i < C * 4; i += 256) wsm[i] = wgt[co * C * 4 + i];
  __syncthreads();
  if (p >= NQ) return;
  const int oh = p / 40, ow = p - oh * 40;
  const float* inb = in + (size_t)b * C * N + (oh * 2) * W + ow * 2;
  float acc = bias[co];
  for (int ci = 0; ci < C; ++ci) {
    const float* xp = inb + ci * N;
    const float* wp = wsm + ci * 4;
    acc = fmaf(wp[0], xp[0], acc);
    acc = fmaf(wp[1], xp[1], acc);
    acc = fmaf(wp[2], xp[W], acc);
    acc = fmaf(wp[3], xp[W + 1], acc);
  }
  outT[((size_t)b * NQ + p) * C + co] = acc;
}

// ---------------- fused 1x1 projections: v (fp32), pv (bf16), pq_t/pk_t (bf16 transposed) ----
__global__ void proj_k(const float* __restrict__ feat1,
                       const float* __restrict__ cvw, const float* __restrict__ cvb,
                       const float* __restrict__ pvw, const float* __restrict__ pvb2,
                       const float* __restrict__ pqw, const float* __restrict__ pqb,
                       const float* __restrict__ pkw, const float* __restrict__ pkb,
                       float* __restrict__ vb, unsigned short* __restrict__ pvh,
                       unsigned short* __restrict__ pq_t, unsigned short* __restrict__ pk_t) {
  const int b = blockIdx.z, co = blockIdx.y;  // co in [0,144)
  const int p = blockIdx.x * 256 + threadIdx.x;
  const float* wsel;
  float bias;
  if (co < 64) { wsel = cvw + co * C; bias = cvb[co]; }
  else if (co < 128) { wsel = pvw + (co - 64) * C; bias = pvb2[co - 64]; }
  else if (co < 136) { wsel = pqw + (co - 128) * C; bias = pqb[co - 128]; }
  else { wsel = pkw + (co - 136) * C; bias = pkb[co - 136]; }
  __shared__ float wsm[C];
  if (threadIdx.x < C) wsm[threadIdx.x] = wsel[threadIdx.x];
  __syncthreads();
  float acc = bias;
  const float* inb = feat1 + (size_t)b * C * N + p;
#pragma unroll 8
  for (int ci = 0; ci < C; ++ci) acc = fmaf(wsm[ci], inb[ci * N], acc);
  if (co < 64) vb[((size_t)b * C + co) * N + p] = acc;
  else if (co < 128) pvh[((size_t)b * C + (co - 64)) * N + p] = f2bf(acc);
  else if (co < 136) pq_t[(size_t)(b * N + p) * 8 + (co - 128)] = f2bf(acc);
  else pk_t[(size_t)(b * N + p) * 8 + (co - 136)] = f2bf(acc);
}

// ---------------- CAM: energy + (max - e) softmax fused (transposed inputs) ----------------
__global__ __launch_bounds__(64) void cam_attn_k(const float* __restrict__ qT,
                                                 const float* __restrict__ kT,
                                                 float* __restrict__ attn) {
  const int b = blockIdx.y, c = blockIdx.x, d = threadIdx.x;  // block = 64 threads
  const float* qp = qT + (size_t)b * NQ * C + c;
  const float* kp = kT + (size_t)b * NQ * C + d;
  float s0 = 0.f, s1 = 0.f, s2 = 0.f, s3 = 0.f;
  for (int n = 0; n < NQ; n += 4) {
    s0 = fmaf(qp[(n + 0) * C], kp[(n + 0) * C], s0);
    s1 = fmaf(qp[(n + 1) * C], kp[(n + 1) * C], s1);
    s2 = fmaf(qp[(n + 2) * C], kp[(n + 2) * C], s2);
    s3 = fmaf(qp[(n + 3) * C], kp[(n + 3) * C], s3);
  }
  const float e = (s0 + s1) + (s2 + s3);
  float rmax = e;
#pragma unroll
  for (int m = 1; m < 64; m <<= 1) rmax = fmaxf(rmax, __shfl_xor(rmax, m));
  const float e2 = rmax - e;
  float m2 = e2;
#pragma unroll
  for (int m = 1; m < 64; m <<= 1) m2 = fmaxf(m2, __shfl_xor(m2, m));
  const float pexp = __expf(e2 - m2);
  float ssum = pexp;
#pragma unroll
  for (int m = 1; m < 64; m <<= 1) ssum += __shfl_xor(ssum, m);
  attn[((size_t)b * C + c) * C + d] = pexp / ssum;
}

// ---------------- PAM flash v2: MFMA scores (K=8 in quad0) + online softmax + MFMA PV ------
// A-row permutation trick: MFMA0 rows map to m = 8*(rr>>2)+(rr&3), MFMA1 +4, so the score
// C-layout gives lane(quad q) exactly m = 8q..8q+7 — the PV B-fragment layout. No shuffles.
__global__ __launch_bounds__(256) void pam_flash_k(
    const unsigned short* __restrict__ pq_t, const unsigned short* __restrict__ pk_t,
    const unsigned short* __restrict__ pvh,
    float* __restrict__ scp, float* __restrict__ Mp, float* __restrict__ Lp) {
  const int b = blockIdx.z, mc = blockIdx.y, nt = blockIdx.x;  // nt < 50
  const int t = threadIdx.x;
  const int wv = t >> 6, lane = t & 63;
  const int ln15 = lane & 15, quad = lane >> 4;
  const int nb = nt * 128 + wv * 32;   // wave covers 32 n
  const int m0c = mc * MCH;

  const unsigned short* pkt = pk_t + ((size_t)b * N + m0c) * 8;
  const unsigned short* pqt = pq_t + (size_t)b * N * 8;
  const unsigned short* pvb = pvh + (size_t)b * C * N;

  U4H8 qf[2];
  qf[0].u = make_uint4(0, 0, 0, 0);
  qf[1].u = make_uint4(0, 0, 0, 0);
  if (quad == 0) {
    qf[0].u = *(const uint4*)&pqt[(size_t)(nb + ln15) * 8];
    qf[1].u = *(const uint4*)&pqt[(size_t)(nb + 16 + ln15) * 8];
  }

  f32x4 acc[2][4];
#pragma unroll
  for (int ns = 0; ns < 2; ++ns)
#pragma unroll
    for (int i = 0; i < 4; ++i) acc[ns][i] = (f32x4){0.f, 0.f, 0.f, 0.f};
  float m_run[2] = {-1e30f, -1e30f}, l_run[2] = {0.f, 0.f};
  const f32x4 zf = {0.f, 0.f, 0.f, 0.f};

  for (int mt = 0; mt < MCH / 32; ++mt) {
    const int ml = mt * 32;
    // score A-fragments (pk side): real data in quad0 only
    U4H8 ak0, ak1;
    ak0.u = make_uint4(0, 0, 0, 0);
    ak1.u = make_uint4(0, 0, 0, 0);
    if (quad == 0) {
      const int mg = ml + ((ln15 >> 2) << 3) + (ln15 & 3);
      ak0.u = *(const uint4*)&pkt[(size_t)mg * 8];
      ak1.u = *(const uint4*)&pkt[(size_t)(mg + 4) * 8];
    }
    // PV A-fragments (pv side): c = ln15 + 16*t4, k(m_local) = quad*8 + i
    const int mgv = m0c + ml + quad * 8;
    U4H8 afr[4];
#pragma unroll
    for (int t4 = 0; t4 < 4; ++t4)
      afr[t4].u = *(const uint4*)&pvb[(size_t)(ln15 + 16 * t4) * N + mgv];

#pragma unroll
    for (int ns = 0; ns < 2; ++ns) {
      f32x4 s0 = __builtin_amdgcn_mfma_f32_16x16x32_bf16(ak0.h, qf[ns].h, zf, 0, 0, 0);
      f32x4 s1 = __builtin_amdgcn_mfma_f32_16x16x32_bf16(ak1.h, qf[ns].h, zf, 0, 0, 0);
      // lane(quad q): s0 = S[m=8q+r][n], s1 = S[m=8q+4+r][n]
      float tmax = fmaxf(fmaxf(fmaxf(s0.x, s0.y), fmaxf(s0.z, s0.w)),
                         fmaxf(fmaxf(s1.x, s1.y), fmaxf(s1.z, s1.w)));
      tmax = fmaxf(tmax, __shfl_xor(tmax, 16));
      tmax = fmaxf(tmax, __shfl_xor(tmax, 32));
      const float m_new = fmaxf(m_run[ns], tmax);
      const float alpha = __expf(m_run[ns] - m_new);
      const float e0 = __expf(s0.x - m_new), e1 = __expf(s0.y - m_new);
      const float e2 = __expf(s0.z - m_new), e3 = __expf(s0.w - m_new);
      const float e4 = __expf(s1.x - m_new), e5 = __expf(s1.y - m_new);
      const float e6 = __expf(s1.z - m_new), e7 = __expf(s1.w - m_new);
      l_run[ns] = fmaf(l_run[ns], alpha,
                       ((e0 + e1) + (e2 + e3)) + ((e4 + e5) + (e6 + e7)));
      m_run[ns] = m_new;
      WBU wb;
      wb.h2[0] = __float22bfloat162_rn(make_float2(e0, e1));
      wb.h2[1] = __float22bfloat162_rn(make_float2(e2, e3));
      wb.h2[2] = __float22bfloat162_rn(make_float2(e4, e5));
      wb.h2[3] = __float22bfloat162_rn(make_float2(e6, e7));
#pragma unroll
      for (int t4 = 0; t4 < 4; ++t4) {
        acc[ns][t4].x *= alpha; acc[ns][t4].y *= alpha;
        acc[ns][t4].z *= alpha; acc[ns][t4].w *= alpha;
        acc[ns][t4] = __builtin_amdgcn_mfma_f32_16x16x32_bf16(afr[t4].h, wb.h, acc[ns][t4], 0, 0, 0);
      }
    }
  }

  float* outp = scp + ((size_t)(mc * B + b)) * C * N;
#pragma unroll
  for (int ns = 0; ns < 2; ++ns) {
    const int n_g = nb + ns * 16 + ln15;
    float lt = l_run[ns];
    lt += __shfl_xor(lt, 16);
    lt += __shfl_xor(lt, 32);
    if (quad == 0) {
      const size_t si = (size_t)mc * (B * N) + (size_t)b * N + n_g;
      Mp[si] = m_run[ns];
      Lp[si] = lt;
    }
#pragma unroll
    for (int t4 = 0; t4 < 4; ++t4) {
      const int co = t4 * 16 + quad * 4;
      outp[(size_t)(co + 0) * N + n_g] = acc[ns][t4].x;
      outp[(size_t)(co + 1) * N + n_g] = acc[ns][t4].y;
      outp[(size_t)(co + 2) * N + n_g] = acc[ns][t4].z;
      outp[(size_t)(co + 3) * N + n_g] = acc[ns][t4].w;
    }
  }
}

// ---------------- PAM merge: per-n combine factors f_s = exp(M_s - M)/L ----------------
__global__ void pam_merge2_k(const float* __restrict__ Mp, const float* __restrict__ Lp,
                             float* __restrict__ Fs) {
  const int ng = blockIdx.x * 256 + threadIdx.x;
  float M = -1e30f;
#pragma unroll
  for (int s = 0; s < SAP; ++s) M = fmaxf(M, Mp[(size_t)s * (B * N) + ng]);
  float L = 0.f;
#pragma unroll
  for (int s = 0; s < SAP; ++s)
    L = fmaf(Lp[(size_t)s * (B * N) + ng], __expf(Mp[(size_t)s * (B * N) + ng] - M), L);
  const float invL = 1.f / L;
#pragma unroll
  for (int s = 0; s < SAP; ++s)
    Fs[(size_t)s * (B * N) + ng] = __expf(Mp[(size_t)s * (B * N) + ng] - M) * invL;
}

// ---------------- combine: feat1 + g1*(attn_c @ v) + g2*Σ_s scp_s*f_s ----------------
__global__ void combine_k(const float* __restrict__ attn, const float* __restrict__ v,
                          const float* __restrict__ feat1, const float* __restrict__ scp,
                          const float* __restrict__ Fs,
                          const float* __restrict__ g1, const float* __restrict__ g2,
                          float* __restrict__ fsum) {
  const int b = blockIdx.z, c = blockIdx.y;
  const int p = blockIdx.x * 256 + threadIdx.x;
  __shared__ float as_[C];
  if (threadIdx.x < C) as_[threadIdx.x] = attn[((size_t)b * C + c) * C + threadIdx.x];
  __syncthreads();
  float acc = 0.f;
  const float* vb = v + (size_t)b * C * N + p;
#pragma unroll 8
  for (int d = 0; d < C; ++d) acc = fmaf(as_[d], vb[d * N], acc);
  const size_t idx = ((size_t)b * C + c) * N + p;
  float sc = 0.f;
#pragma unroll
  for (int s = 0; s < SAP; ++s)
    sc = fmaf(scp[(size_t)s * B * C * N + idx], Fs[(size_t)s * (B * N) + b * N + p], sc);
  fsum[idx] = fmaf(g1[0], acc, fmaf(g2[0], sc, feat1[idx]));
}

}  // namespace

extern "C" void kernel_launch(void* const* d_in, const int* in_sizes, int n_in,
                              void* d_out, int out_size, void* d_ws, size_t ws_size,
                              hipStream_t stream) {
  (void)in_sizes; (void)n_in; (void)out_size; (void)ws_size;
  const float* x    = (const float*)d_in[0];
  const float* Wc   = (const float*)d_in[1];
  const float* bn1g = (const float*)d_in[2];
  const float* bn1b = (const float*)d_in[3];
  const float* cqw  = (const float*)d_in[4];
  const float* cqb  = (const float*)d_in[5];
  const float* ckw  = (const float*)d_in[6];
  const float* ckb  = (const float*)d_in[7];
  const float* cvw  = (const float*)d_in[8];
  const float* cvb  = (const float*)d_in[9];
  const float* pqw  = (const float*)d_in[10];
  const float* pqb  = (const float*)d_in[11];
  const float* pkw  = (const float*)d_in[12];
  const float* pkb  = (const float*)d_in[13];
  const float* pvw  = (const float*)d_in[14];
  const float* pvb  = (const float*)d_in[15];
  const float* g1   = (const float*)d_in[16];
  const float* g2   = (const float*)d_in[17];
  const float* bn2g = (const float*)d_in[18];
  const float* bn2b = (const float*)d_in[19];
  const float* Wd   = (const float*)d_in[20];
  const float* bn3g = (const float*)d_in[21];
  const float* bn3b = (const float*)d_in[22];
  float* out = (float*)d_out;

  float* wsp = (float*)d_ws;
  size_t off = 0;
  auto alloc = [&](size_t nel) { float* p = wsp + off; off += nel; return p; };
  float* feat1 = alloc((size_t)B * C * N);
  float* y1    = alloc((size_t)B * C * N);
  float* qT    = alloc((size_t)B * NQ * C);
  float* kT    = alloc((size_t)B * NQ * C);
  float* vb    = alloc((size_t)B * C * N);
  float* attn  = alloc((size_t)B * C * C);
  unsigned short* pvh  = (unsigned short*)alloc((size_t)B * C * N / 2);
  unsigned short* pq_t = (unsigned short*)alloc((size_t)B * N * 4);   // B*N*8 shorts
  unsigned short* pk_t = (unsigned short*)alloc((size_t)B * N * 4);
  float* scp   = alloc((size_t)SAP * B * C * N);
  float* Mp    = alloc((size_t)SAP * B * N);
  float* Lp    = alloc((size_t)SAP * B * N);
  float* Fs    = alloc((size_t)SAP * B * N);
  float* fsum  = alloc((size_t)B * C * N);
  float* y3    = alloc((size_t)B * C * N);
  unsigned short* xt  = (unsigned short*)alloc((size_t)B * N * C / 2);
  unsigned short* x2t = (unsigned short*)alloc((size_t)B * N * C / 2);
  unsigned short* w9c = (unsigned short*)alloc((size_t)9 * C * C / 2);
  unsigned short* w9d = (unsigned short*)alloc((size_t)9 * C * C / 2);
  float* mean1 = alloc(C); float* istd1 = alloc(C);
  float* mean2 = alloc(C); float* istd2 = alloc(C);
  float* mean3 = alloc(C); float* istd3 = alloc(C);

  // weight transforms (independent)
  wxform_k<<<dim3(36), 256, 0, stream>>>(Wc, w9c);
  wxform_k<<<dim3(36), 256, 0, stream>>>(Wd, w9d);
  // conv_c -> bn1 -> relu
  to_nhwc_k<<<dim3(B * N / 256), 256, 0, stream>>>(x, xt);
  conv3x3_mfma_k<<<dim3(N / 16, B), 64, 0, stream>>>(xt, w9c, y1);
  bn_stats_k<<<dim3(C), 1024, 0, stream>>>(y1, mean1, istd1);
  bn_apply_k<<<dim3(B * C * N / 256), 256, 0, stream>>>(y1, mean1, istd1, bn1g, bn1b, feat1, 1);
  // CAM q/k (one launch, transposed outputs)
  conv2x2T_k<<<dim3(7, C, B * 2), 256, 0, stream>>>(feat1, cqw, cqb, ckw, ckb, qT, kT);
  // fused 1x1 projections: v, pv(bf16), pq_t/pk_t (bf16 transposed)
  proj_k<<<dim3(N / 256, 144, B), 256, 0, stream>>>(feat1, cvw, cvb, pvw, pvb, pqw, pqb,
                                                    pkw, pkb, vb, pvh, pq_t, pk_t);
  // CAM attention
  cam_attn_k<<<dim3(C, B), 64, 0, stream>>>(qT, kT, attn);
  // PAM flash attention (MFMA scores + PV) + merge
  pam_flash_k<<<dim3(N / 128, SAP, B), 256, 0, stream>>>(pq_t, pk_t, pvh, scp, Mp, Lp);
  pam_merge2_k<<<dim3(B * N / 256), 256, 0, stream>>>(Mp, Lp, Fs);
  // combine
  combine_k<<<dim3(N / 256, C, B), 256, 0, stream>>>(attn, vb, feat1, scp, Fs, g1, g2, fsum);
  // bn2 -> conv_d -> bn3 -> relu
  bn_stats_k<<<dim3(C), 1024, 0, stream>>>(fsum, mean2, istd2);
  bn2_nhwc_k<<<dim3(B * N / 256), 256, 0, stream>>>(fsum, mean2, istd2, bn2g, bn2b, x2t);
  conv3x3_mfma_k<<<dim3(N / 16, B), 64, 0, stream>>>(x2t, w9d, y3);
  bn_stats_k<<<dim3(C), 1024, 0, stream>>>(y3, mean3, istd3);
  bn_apply_k<<<dim3(B * C * N / 256), 256, 0, stream>>>(y3, mean3, istd3, bn3g, bn3b, out, 1);
}